// Round 6
// baseline (132.392 us; speedup 1.0000x reference)
//
#include <hip/hip_runtime.h>
#include <math.h>

#define NTOK 100
#define EDIM 5
#define NH   4
#define NL   3
#define DD   64
#define BLK  256
#define LOG2E 1.4426950408889634f

// ---------------------------------------------------------------------------
// Kernel 1: fold per-head projections into 5x5 matrices (unchanged, verified).
//   M[l][h] = (1/8) * Wq^T Wk ; P[l][h] = Wv^T Wo_h^T
// ws layout: float [2][NL][NH][EDIM][8]
// ---------------------------------------------------------------------------
__global__ void precompute_mp(const float* __restrict__ Wq,
                              const float* __restrict__ Wk,
                              const float* __restrict__ Wv,
                              const float* __restrict__ Wo,
                              float* __restrict__ mp) {
  const int blk = blockIdx.x;
  const int which = blk / 12;
  const int rem = blk % 12;
  const int l = rem / 4, h = rem % 4;
  const int t = threadIdx.x;

  __shared__ float A[320];
  __shared__ float Bsh[320];

  const float* wa = (which ? Wv : Wq) + (l*NH + h)*DD*EDIM;
  for (int r = t; r < 320; r += 64) A[r] = wa[r];
  if (which == 0) {
    const float* wk = Wk + (l*NH + h)*DD*EDIM;
    for (int r = t; r < 320; r += 64) Bsh[r] = wk[r];
  } else {
    for (int r = t; r < 320; r += 64) {
      int f = r >> 6, d = r & 63;
      Bsh[r] = Wo[(l*EDIM + f)*(NH*DD) + h*DD + d];
    }
  }
  __syncthreads();
  if (t < 25) {
    int e = t / 5, f = t % 5;
    float acc = 0.f;
    if (which == 0) {
      #pragma unroll 8
      for (int d = 0; d < DD; ++d) acc += A[d*5+e] * Bsh[d*5+f];
      acc *= 0.125f;
    } else {
      #pragma unroll 8
      for (int d = 0; d < DD; ++d) acc += A[d*5+e] * Bsh[f*64+d];
    }
    mp[which*960 + ((l*NH + h)*EDIM + e)*8 + f] = acc;
  }
}

// ---------------------------------------------------------------------------
// Kernel 2: ONE WAVE PER BATCH. 4 independent waves per 256-block; a single
// __syncthreads after the shared M/P load, then zero barriers. Lane i owns
// compacted token-row i (state in regs); j-broadcasts via wave-uniform LDS
// reads of the wave's private state slice. Rare nm>=64 batches (P~0.35%)
// take a fused 2-rows-per-lane path under a wave-uniform branch.
// ---------------------------------------------------------------------------
__global__ __launch_bounds__(BLK, 1) void encoder_kernel(
    const float* __restrict__ x,
    const float* __restrict__ mp,
    const float* __restrict__ Wf,
    const float* __restrict__ bfv,
    const float* __restrict__ g1,
    const float* __restrict__ b1,
    const float* __restrict__ g2,
    const float* __restrict__ b2,
    float* __restrict__ out)
{
  const int wv   = threadIdx.x >> 6;
  const int lane = threadIdx.x & 63;
  const int b    = blockIdx.x * 4 + wv;

  __shared__ float s_mp[1920];               // M then P, [.][5][8] rows
  __shared__ float s_st[4][NTOK+1][8];       // per-wave token state (32B rows)
  __shared__ int   s_cidx[4][NTOK];          // token -> compact slot (nm if masked)

  for (int r = threadIdx.x; r < 480; r += BLK)
    ((float4*)s_mp)[r] = ((const float4*)mp)[r];
  __syncthreads();                           // the ONLY block barrier

  float* st  = &s_st[wv][0][0];
  int* cidx  = s_cidx[wv];

  // ---- setup: in-wave ballot compaction, state -> LDS slice + regs ----
  const float* xb = x + b*300;
  const int t1 = lane, t2 = lane + 64;
  float k0a = xb[3*t1], k1a = xb[3*t1+1], k2a = xb[3*t1+2];
  bool m1 = (k2a > 0.f);
  float k0b = 0.f, k1b = 0.f, k2b = 0.f; bool m2 = false;
  if (t2 < NTOK) {
    k0b = xb[3*t2]; k1b = xb[3*t2+1]; k2b = xb[3*t2+2];
    m2 = (k2b > 0.f);
  }
  unsigned long long bm1 = __ballot(m1);
  unsigned long long bm2 = __ballot(m2);
  const int pc1 = __popcll(bm1);
  const int nm  = pc1 + __popcll(bm2);       // unmasked count
  const int ns  = nm + 1;                    // + rep slot
  unsigned long long below = (lane == 0) ? 0ull : ((1ull << lane) - 1ull);
  int p1 = __popcll(bm1 & below);
  int p2 = pc1 + __popcll(bm2 & below);
  if (m1) {
    *(float4*)(st + p1*8) = make_float4(k0a, k1a, k2a, sinf((float)t1));
    st[p1*8+4] = cosf((float)t1);
  }
  cidx[t1] = m1 ? p1 : nm;
  if (t2 < NTOK) {
    if (m2) {
      *(float4*)(st + p2*8) = make_float4(k0b, k1b, k2b, sinf((float)t2));
      st[p2*8+4] = cosf((float)t2);
    }
    cidx[t2] = m2 ? p2 : nm;
  }
  if (lane == 0) {                           // rep (masked) token starts at 0
    *(float4*)(st + nm*8) = make_float4(0.f,0.f,0.f,0.f);
    st[nm*8+4] = 0.f;
  }
  // wave-local LDS ordering: lgkmcnt only, no barrier needed.

  const bool slow = (ns > 64);               // ~0.35% of batches
  const int  rB   = lane + 64;
  const bool act1 = (lane < ns);
  const bool act2 = slow && (rB < ns);
  const bool rep1 = (lane == nm);
  const bool rep2 = (rB == nm);

  float o[5], o2[5] = {0,0,0,0,0};
  {
    float4 v = *(const float4*)(st + lane*8);
    o[0]=v.x; o[1]=v.y; o[2]=v.z; o[3]=v.w; o[4]=st[lane*8+4];
  }
  if (act2) {
    float4 v = *(const float4*)(st + rB*8);
    o2[0]=v.x; o2[1]=v.y; o2[2]=v.z; o2[3]=v.w; o2[4]=st[rB*8+4];
  }

  for (int l = 0; l < NL; ++l) {
    float a[NH][5], a2[NH][5], w[NH][5], w2[NH][5], ls[NH], ls2[NH];
    const float* Ml = s_mp + l*NH*40;

    #pragma unroll
    for (int h = 0; h < NH; ++h) {
      const float* Mh = Ml + h*40;
      float A0=0.f,A1=0.f,A2=0.f,A3=0.f,A4=0.f;
      #pragma unroll
      for (int e = 0; e < 5; ++e) {
        float4 mr = *(const float4*)(Mh + e*8);
        float  m4 = Mh[e*8+4];
        A0 += o[e]*mr.x; A1 += o[e]*mr.y; A2 += o[e]*mr.z; A3 += o[e]*mr.w; A4 += o[e]*m4;
      }
      a[h][0]=A0*LOG2E; a[h][1]=A1*LOG2E; a[h][2]=A2*LOG2E;
      a[h][3]=A3*LOG2E; a[h][4]=A4*LOG2E;
      ls[h] = 0.f;
      #pragma unroll
      for (int f = 0; f < 5; ++f) w[h][f] = 0.f;
    }
    if (slow) {
      #pragma unroll
      for (int h = 0; h < NH; ++h) {
        const float* Mh = Ml + h*40;
        float A0=0.f,A1=0.f,A2=0.f,A3=0.f,A4=0.f;
        #pragma unroll
        for (int e = 0; e < 5; ++e) {
          float4 mr = *(const float4*)(Mh + e*8);
          float  m4 = Mh[e*8+4];
          A0 += o2[e]*mr.x; A1 += o2[e]*mr.y; A2 += o2[e]*mr.z; A3 += o2[e]*mr.w; A4 += o2[e]*m4;
        }
        a2[h][0]=A0*LOG2E; a2[h][1]=A1*LOG2E; a2[h][2]=A2*LOG2E;
        a2[h][3]=A3*LOG2E; a2[h][4]=A4*LOG2E;
        ls2[h] = 0.f;
        #pragma unroll
        for (int f = 0; f < 5; ++f) w2[h][f] = 0.f;
      }
    }

    // ---- attention j-loop: wave-uniform LDS broadcasts, no barriers ----
    if (!slow) {
      #pragma unroll 2
      for (int j = 0; j < nm; ++j) {
        float4 oj4 = *(const float4*)(st + j*8);
        float  oj5 = st[j*8+4];
        float oj[5] = {oj4.x, oj4.y, oj4.z, oj4.w, oj5};
        #pragma unroll
        for (int h = 0; h < NH; ++h) {
          float s = a[h][0]*oj[0]+a[h][1]*oj[1]+a[h][2]*oj[2]+a[h][3]*oj[3]+a[h][4]*oj[4];
          float p = __builtin_amdgcn_exp2f(s);
          p = rep1 ? 1.f : p;
          ls[h] += p;
          #pragma unroll
          for (int e = 0; e < 5; ++e) w[h][e] += p*oj[e];
        }
      }
    } else {
      #pragma unroll 2
      for (int j = 0; j < nm; ++j) {
        float4 oj4 = *(const float4*)(st + j*8);
        float  oj5 = st[j*8+4];
        float oj[5] = {oj4.x, oj4.y, oj4.z, oj4.w, oj5};
        #pragma unroll
        for (int h = 0; h < NH; ++h) {
          float sA = a[h][0]*oj[0]+a[h][1]*oj[1]+a[h][2]*oj[2]+a[h][3]*oj[3]+a[h][4]*oj[4];
          float sB = a2[h][0]*oj[0]+a2[h][1]*oj[1]+a2[h][2]*oj[2]+a2[h][3]*oj[3]+a2[h][4]*oj[4];
          float pA = __builtin_amdgcn_exp2f(sA);  // rep impossible on row1 here
          float pB = __builtin_amdgcn_exp2f(sB);
          pB = rep2 ? 1.f : pB;
          ls[h] += pA; ls2[h] += pB;
          #pragma unroll
          for (int e = 0; e < 5; ++e) { w[h][e] += pA*oj[e]; w2[h][e] += pB*oj[e]; }
        }
      }
    }

    // ---- token pass (lane-local): P-apply, +res, LN1, FFN, +res, LN2 ----
    auto token_pass = [&](float* o_, float (*w_)[5], float* ls_,
                          bool isrep, bool active, int row) {
      float wext = isrep ? (float)(NTOK - nm) : 0.f;
      float c[5] = {0.f,0.f,0.f,0.f,0.f};
      const float* Pl = s_mp + 960 + l*NH*40;
      #pragma unroll
      for (int h = 0; h < NH; ++h) {
        float inv = isrep ? 0.01f : 1.f/ls_[h];
        const float* Ph = Pl + h*40;
        #pragma unroll
        for (int f = 0; f < 5; ++f) {
          float wn = (w_[h][f] + wext*o_[f]) * inv;
          float4 pr = *(const float4*)(Ph + f*8);
          float  p4 = Ph[f*8+4];
          c[0]+=wn*pr.x; c[1]+=wn*pr.y; c[2]+=wn*pr.z; c[3]+=wn*pr.w; c[4]+=wn*p4;
        }
      }
      float y[5];
      #pragma unroll
      for (int e = 0; e < 5; ++e) y[e] = o_[e] + c[e];
      float mu = 0.2f*(y[0]+y[1]+y[2]+y[3]+y[4]);
      float var = 0.f;
      #pragma unroll
      for (int e = 0; e < 5; ++e) { float d = y[e]-mu; var += d*d; }
      var *= 0.2f;
      float inv1 = 1.f/sqrtf(var + 1e-5f);
      float ln1[5];
      #pragma unroll
      for (int e = 0; e < 5; ++e) ln1[e] = (y[e]-mu)*inv1*g1[l*5+e] + b1[l*5+e];
      float rr[5];
      #pragma unroll
      for (int e = 0; e < 5; ++e) {
        float acc = bfv[l*5+e];
        #pragma unroll
        for (int f = 0; f < 5; ++f) acc += ln1[f]*Wf[(l*5+e)*5+f];
        acc = acc > 0.f ? acc : 0.f;
        rr[e] = acc + ln1[e];
      }
      float mu2 = 0.2f*(rr[0]+rr[1]+rr[2]+rr[3]+rr[4]);
      float var2 = 0.f;
      #pragma unroll
      for (int e = 0; e < 5; ++e) { float d = rr[e]-mu2; var2 += d*d; }
      var2 *= 0.2f;
      float inv2 = 1.f/sqrtf(var2 + 1e-5f);
      float n0 = (rr[0]-mu2)*inv2*g2[l*5+0] + b2[l*5+0];
      float n1 = (rr[1]-mu2)*inv2*g2[l*5+1] + b2[l*5+1];
      float n2 = (rr[2]-mu2)*inv2*g2[l*5+2] + b2[l*5+2];
      float n3 = (rr[3]-mu2)*inv2*g2[l*5+3] + b2[l*5+3];
      float n4 = (rr[4]-mu2)*inv2*g2[l*5+4] + b2[l*5+4];
      o_[0]=n0; o_[1]=n1; o_[2]=n2; o_[3]=n3; o_[4]=n4;
      if (active) {
        *(float4*)(st + row*8) = make_float4(n0,n1,n2,n3);
        st[row*8+4] = n4;
      }
    };
    token_pass(o,  w,  ls,  rep1, act1, lane);
    if (slow) token_pass(o2, w2, ls2, rep2, act2, rB);
  }

  // ---- expand compacted state back to [N, E], coalesced stores ----
  const int obase = b*(NTOK*EDIM);
  #pragma unroll
  for (int rr = 0; rr < 8; ++rr) {
    int idx = rr*64 + lane;
    if (idx < NTOK*EDIM) {
      int tok = idx / 5;                 // compile-time divisor -> mul/shift
      int e = idx - tok*5;
      int c = cidx[tok];
      out[obase + idx] = st[c*8 + e];
    }
  }
}

extern "C" void kernel_launch(void* const* d_in, const int* in_sizes, int n_in,
                              void* d_out, int out_size, void* d_ws, size_t ws_size,
                              hipStream_t stream) {
  const float* x  = (const float*)d_in[0];
  const float* Wq = (const float*)d_in[1];
  const float* Wk = (const float*)d_in[2];
  const float* Wv = (const float*)d_in[3];
  const float* Wo = (const float*)d_in[4];
  const float* Wf = (const float*)d_in[5];
  const float* bf = (const float*)d_in[6];
  const float* g1 = (const float*)d_in[7];
  const float* b1 = (const float*)d_in[8];
  const float* g2 = (const float*)d_in[9];
  const float* b2 = (const float*)d_in[10];
  float* outp = (float*)d_out;
  float* mp   = (float*)d_ws;   // 1920 floats

  precompute_mp<<<24, 64, 0, stream>>>(Wq, Wk, Wv, Wo, mp);
  encoder_kernel<<<256, BLK, 0, stream>>>(x, mp, Wf, bf, g1, b1, g2, b2, outp);
}

// Round 7
// 128.176 us; speedup vs baseline: 1.0329x; 1.0329x over previous
//
#include <hip/hip_runtime.h>
#include <math.h>

#define NTOK 100
#define EDIM 5
#define NH   4
#define NL   3
#define DD   64
#define BLK  256
#define LOG2E 1.4426950408889634f

// ---------------------------------------------------------------------------
// Kernel 1: fold per-head projections into 5x5 matrices (verified r4/r6).
//   M[l][h] = (1/8) * Wq^T Wk ; P[l][h] = Wv^T Wo_h^T
// ws layout: float [2][NL][NH][EDIM][8]
// ---------------------------------------------------------------------------
__global__ void precompute_mp(const float* __restrict__ Wq,
                              const float* __restrict__ Wk,
                              const float* __restrict__ Wv,
                              const float* __restrict__ Wo,
                              float* __restrict__ mp) {
  const int blk = blockIdx.x;
  const int which = blk / 12;
  const int rem = blk % 12;
  const int l = rem / 4, h = rem % 4;
  const int t = threadIdx.x;

  __shared__ float A[320];
  __shared__ float Bsh[320];

  const float* wa = (which ? Wv : Wq) + (l*NH + h)*DD*EDIM;
  for (int r = t; r < 320; r += 64) A[r] = wa[r];
  if (which == 0) {
    const float* wk = Wk + (l*NH + h)*DD*EDIM;
    for (int r = t; r < 320; r += 64) Bsh[r] = wk[r];
  } else {
    for (int r = t; r < 320; r += 64) {
      int f = r >> 6, d = r & 63;
      Bsh[r] = Wo[(l*EDIM + f)*(NH*DD) + h*DD + d];
    }
  }
  __syncthreads();
  if (t < 25) {
    int e = t / 5, f = t % 5;
    float acc = 0.f;
    if (which == 0) {
      #pragma unroll 8
      for (int d = 0; d < DD; ++d) acc += A[d*5+e] * Bsh[d*5+f];
      acc *= 0.125f;
    } else {
      #pragma unroll 8
      for (int d = 0; d < DD; ++d) acc += A[d*5+e] * Bsh[f*64+d];
    }
    mp[which*960 + ((l*NH + h)*EDIM + e)*8 + f] = acc;
  }
}

// ---------------------------------------------------------------------------
// Kernel 2: one BLOCK per batch, one WAVE per head (4 waves). Lane = compacted
// row. 16 waves/CU (vs round-6's 4) restores latency hiding; j-loop is ~13
// VALU/iter per wave. Two barriers per layer; token pass on wave 0 only
// (hidden by the other 3 blocks/CU). Rare ns>64 handled by a sequential
// `half` loop (register reuse -> no VGPR inflation).
// ---------------------------------------------------------------------------
__global__ __launch_bounds__(BLK) void encoder_kernel(
    const float* __restrict__ x,
    const float* __restrict__ mp,
    const float* __restrict__ Wf,
    const float* __restrict__ bfv,
    const float* __restrict__ g1,
    const float* __restrict__ b1,
    const float* __restrict__ g2,
    const float* __restrict__ b2,
    float* __restrict__ out)
{
  const int wv   = threadIdx.x >> 6;     // head index
  const int lane = threadIdx.x & 63;
  const int b    = blockIdx.x;

  __shared__ float s_mp[1920];           // M then P, rows [5][8]
  __shared__ float s_st[104][8];         // compacted token state
  __shared__ float s_w[NH][104][8];      // {w0..w4, ls, -, -} per (head,row)
  __shared__ int   s_cidx[NTOK];

  for (int r = threadIdx.x; r < 480; r += BLK)
    ((float4*)s_mp)[r] = ((const float4*)mp)[r];

  // ---- setup: all 4 waves compute ballots redundantly (identical data);
  //      wave 0 writes state/cidx. One barrier covers mp-load + setup. ----
  const float* xb = x + b*300;
  const int t1 = lane, t2 = lane + 64;
  float k0a = xb[3*t1], k1a = xb[3*t1+1], k2a = xb[3*t1+2];
  bool m1 = (k2a > 0.f);
  float k0b = 0.f, k1b = 0.f, k2b = 0.f; bool m2 = false;
  if (t2 < NTOK) {
    k0b = xb[3*t2]; k1b = xb[3*t2+1]; k2b = xb[3*t2+2];
    m2 = (k2b > 0.f);
  }
  unsigned long long bm1 = __ballot(m1);
  unsigned long long bm2 = __ballot(m2);
  const int pc1 = __popcll(bm1);
  const int nm  = pc1 + __popcll(bm2);   // unmasked count (uniform, all waves)
  const int ns  = nm + 1;                // + rep slot
  if (wv == 0) {
    unsigned long long below = (lane == 0) ? 0ull : ((1ull << lane) - 1ull);
    int p1 = __popcll(bm1 & below);
    int p2 = pc1 + __popcll(bm2 & below);
    if (m1) {
      *(float4*)(&s_st[p1][0]) = make_float4(k0a, k1a, k2a, sinf((float)t1));
      s_st[p1][4] = cosf((float)t1);
    }
    s_cidx[t1] = m1 ? p1 : nm;
    if (t2 < NTOK) {
      if (m2) {
        *(float4*)(&s_st[p2][0]) = make_float4(k0b, k1b, k2b, sinf((float)t2));
        s_st[p2][4] = cosf((float)t2);
      }
      s_cidx[t2] = m2 ? p2 : nm;
    }
    if (lane == 0) {
      *(float4*)(&s_st[nm][0]) = make_float4(0.f,0.f,0.f,0.f);
      s_st[nm][4] = 0.f;
    }
  }
  __syncthreads();

  const int nh2 = (ns > 64) ? 2 : 1;     // uniform across block

  for (int l = 0; l < NL; ++l) {
    // ---- phase 1: per-head j-loops (wave wv = head wv) ----
    for (int half = 0; half < nh2; ++half) {
      const int row = lane + (half << 6);
      const bool active = (row < ns);
      const bool rep = (row == nm);
      const int rr = active ? row : 0;

      float4 ov = *(const float4*)(&s_st[rr][0]);
      float o[5] = {ov.x, ov.y, ov.z, ov.w, s_st[rr][4]};

      const float* Mh = s_mp + (l*NH + wv)*40;
      float a0=0.f,a1=0.f,a2=0.f,a3=0.f,a4=0.f;
      #pragma unroll
      for (int e = 0; e < 5; ++e) {
        float4 mr = *(const float4*)(Mh + e*8);
        float  m4 = Mh[e*8+4];
        a0 += o[e]*mr.x; a1 += o[e]*mr.y; a2 += o[e]*mr.z; a3 += o[e]*mr.w; a4 += o[e]*m4;
      }
      a0*=LOG2E; a1*=LOG2E; a2*=LOG2E; a3*=LOG2E; a4*=LOG2E;

      float ls=0.f, w0=0.f,w1=0.f,w2=0.f,w3=0.f,w4=0.f;
      #pragma unroll 4
      for (int j = 0; j < nm; ++j) {
        float4 oj = *(const float4*)(&s_st[j][0]);   // wave-uniform broadcast
        float  oe = s_st[j][4];
        float s = a0*oj.x + a1*oj.y + a2*oj.z + a3*oj.w + a4*oe;
        float p = __builtin_amdgcn_exp2f(s);
        p = rep ? 1.f : p;
        ls += p;
        w0 += p*oj.x; w1 += p*oj.y; w2 += p*oj.z; w3 += p*oj.w; w4 += p*oe;
      }
      if (active) {
        *(float4*)(&s_w[wv][row][0]) = make_float4(w0, w1, w2, w3);
        *(float2*)(&s_w[wv][row][4]) = make_float2(w4, ls);
      }
    }
    __syncthreads();

    // ---- phase 2: token pass on wave 0 only ----
    if (wv == 0) {
      for (int half = 0; half < nh2; ++half) {
        const int row = lane + (half << 6);
        const bool active = (row < ns);
        const bool rep = (row == nm);
        const int rr = active ? row : 0;

        float4 ov = *(const float4*)(&s_st[rr][0]);
        float o[5] = {ov.x, ov.y, ov.z, ov.w, s_st[rr][4]};
        float wext = rep ? (float)(NTOK - nm) : 0.f;

        float c[5] = {0.f,0.f,0.f,0.f,0.f};
        const float* Pl = s_mp + 960 + l*NH*40;
        #pragma unroll
        for (int h = 0; h < NH; ++h) {
          float4 wa = *(const float4*)(&s_w[h][rr][0]);
          float2 wb = *(const float2*)(&s_w[h][rr][4]);
          float w[5] = {wa.x, wa.y, wa.z, wa.w, wb.x};
          float inv = rep ? 0.01f : 1.f/wb.y;
          const float* Ph = Pl + h*40;
          #pragma unroll
          for (int f = 0; f < 5; ++f) {
            float wn = (w[f] + wext*o[f]) * inv;
            float4 pr = *(const float4*)(Ph + f*8);
            float  p4 = Ph[f*8+4];
            c[0]+=wn*pr.x; c[1]+=wn*pr.y; c[2]+=wn*pr.z; c[3]+=wn*pr.w; c[4]+=wn*p4;
          }
        }
        float y[5];
        #pragma unroll
        for (int e = 0; e < 5; ++e) y[e] = o[e] + c[e];
        float mu = 0.2f*(y[0]+y[1]+y[2]+y[3]+y[4]);
        float var = 0.f;
        #pragma unroll
        for (int e = 0; e < 5; ++e) { float d = y[e]-mu; var += d*d; }
        var *= 0.2f;
        float inv1 = 1.f/sqrtf(var + 1e-5f);
        float ln1[5];
        #pragma unroll
        for (int e = 0; e < 5; ++e) ln1[e] = (y[e]-mu)*inv1*g1[l*5+e] + b1[l*5+e];
        float rv[5];
        #pragma unroll
        for (int e = 0; e < 5; ++e) {
          float acc = bfv[l*5+e];
          #pragma unroll
          for (int f = 0; f < 5; ++f) acc += ln1[f]*Wf[(l*5+e)*5+f];
          acc = acc > 0.f ? acc : 0.f;
          rv[e] = acc + ln1[e];
        }
        float mu2 = 0.2f*(rv[0]+rv[1]+rv[2]+rv[3]+rv[4]);
        float var2 = 0.f;
        #pragma unroll
        for (int e = 0; e < 5; ++e) { float d = rv[e]-mu2; var2 += d*d; }
        var2 *= 0.2f;
        float inv2 = 1.f/sqrtf(var2 + 1e-5f);
        float n0 = (rv[0]-mu2)*inv2*g2[l*5+0] + b2[l*5+0];
        float n1 = (rv[1]-mu2)*inv2*g2[l*5+1] + b2[l*5+1];
        float n2 = (rv[2]-mu2)*inv2*g2[l*5+2] + b2[l*5+2];
        float n3 = (rv[3]-mu2)*inv2*g2[l*5+3] + b2[l*5+3];
        float n4 = (rv[4]-mu2)*inv2*g2[l*5+4] + b2[l*5+4];
        if (active) {
          *(float4*)(&s_st[row][0]) = make_float4(n0, n1, n2, n3);
          s_st[row][4] = n4;
        }
      }
    }
    __syncthreads();
  }

  // ---- expand compacted state back to [N, E], coalesced stores ----
  const int obase = b*(NTOK*EDIM);
  for (int idx = threadIdx.x; idx < NTOK*EDIM; idx += BLK) {
    int tok = idx / 5;
    int e = idx - tok*5;
    int c = s_cidx[tok];
    out[obase + idx] = s_st[c][e];
  }
}

extern "C" void kernel_launch(void* const* d_in, const int* in_sizes, int n_in,
                              void* d_out, int out_size, void* d_ws, size_t ws_size,
                              hipStream_t stream) {
  const float* x  = (const float*)d_in[0];
  const float* Wq = (const float*)d_in[1];
  const float* Wk = (const float*)d_in[2];
  const float* Wv = (const float*)d_in[3];
  const float* Wo = (const float*)d_in[4];
  const float* Wf = (const float*)d_in[5];
  const float* bf = (const float*)d_in[6];
  const float* g1 = (const float*)d_in[7];
  const float* b1 = (const float*)d_in[8];
  const float* g2 = (const float*)d_in[9];
  const float* b2 = (const float*)d_in[10];
  float* outp = (float*)d_out;
  float* mp   = (float*)d_ws;   // 1920 floats

  precompute_mp<<<24, 64, 0, stream>>>(Wq, Wk, Wv, Wo, mp);
  encoder_kernel<<<1024, BLK, 0, stream>>>(x, mp, Wf, bf, g1, b1, g2, b2, outp);
}